// Round 4
// baseline (65.639 us; speedup 1.0000x reference)
//
#include <hip/hip_runtime.h>
#include <stdint.h>

// out[m,p] = sum_k f32(bits(x[m,k]) + bits(weight[p,k]) - OFFSET) + bias[p]
// m=256, n=512, p=512. Pure VALU workload (uint add on bit patterns -> no MFMA).
//
// R4: remove the atomic combine path.
//  - kernel1: same VALU-bound core as R3 (TM=4, KS=4, 512 blocks x 4 waves,
//    XOR-swizzled 64KB LDS w-tile, offset folded at staging), but writes
//    k-split partials to d_ws with plain coalesced stores (no atomics,
//    no d_out memset needed).
//  - kernel2: 128 blocks x 256 threads, float4 reduce of the 4 partial
//    planes (2MB, L2-resident) + bias add -> d_out. ~0.5us.

#define OFFSET_FP32 1064828928u

constexpr int M = 256;
constexpr int N = 512;
constexpr int P = 512;

constexpr int BP = 128;     // p cols per block
constexpr int BM = 8;       // m rows per block
constexpr int TM = 4;       // m rows per thread
constexpr int KS = 4;       // k-split factor
constexpr int KT = N / KS;  // 128 k per block

__global__ __launch_bounds__(256) void lmul_partial_kernel(
    const uint32_t* __restrict__ xb,   // [M][N] bit patterns of x
    const uint32_t* __restrict__ wb,   // [P][N] bit patterns of weight
    float*          __restrict__ pws)  // [KS][M][P] partials
{
    __shared__ uint32_t Bs[BP * KT];   // 64 KB, row pp at pp*KT, granules XOR-swizzled

    const int tid     = threadIdx.x;
    const int p_local = tid & (BP - 1);                            // 0..127
    const int m_quad  = __builtin_amdgcn_readfirstlane(tid >> 7);  // 0..1, wave-uniform

    const int p0 = blockIdx.y * BP;
    const int m0 = blockIdx.x * BM + m_quad * TM;
    const int kz = blockIdx.z;
    const int k0 = kz * KT;

    // ---- stage w tile [128p][128k] = 64KB: 256 threads x 16 uint4 ----
    const int sg = tid & 31;  // 16B granule within row, coalesced
    const int sr = tid >> 5;  // 0..7
    const uint32_t* wbase = wb + (size_t)p0 * N + k0;
    #pragma unroll
    for (int j = 0; j < 16; ++j) {
        const int pp = sr + j * 8;
        uint4 v = *(const uint4*)(wbase + (size_t)pp * N + sg * 4);
        v.x -= OFFSET_FP32; v.y -= OFFSET_FP32;   // fold offset at staging
        v.z -= OFFSET_FP32; v.w -= OFFSET_FP32;
        const int g = sg ^ (pp & 7);              // swizzle: conflict-free b128 r/w
        *(uint4*)&Bs[pp * KT + g * 4] = v;
    }
    __syncthreads();

    // ---- compute: 32 steps x (1 ds_read_b128 + 4 scalar uint4 a-loads + 32 VALU) ----
    const uint32_t* xr0 = xb + (size_t)(m0 + 0) * N + k0;
    const uint32_t* xr1 = xb + (size_t)(m0 + 1) * N + k0;
    const uint32_t* xr2 = xb + (size_t)(m0 + 2) * N + k0;
    const uint32_t* xr3 = xb + (size_t)(m0 + 3) * N + k0;

    float acc[TM][4] = {};
    const uint32_t* brow = &Bs[p_local * KT];
    const int rot = p_local & 7;

    #pragma unroll 8
    for (int j = 0; j < KT / 4; ++j) {
        const uint4 b  = *(const uint4*)&brow[(j ^ rot) * 4];
        const uint4 a0 = *(const uint4*)(xr0 + j * 4);  // wave-uniform -> s_load
        const uint4 a1 = *(const uint4*)(xr1 + j * 4);
        const uint4 a2 = *(const uint4*)(xr2 + j * 4);
        const uint4 a3 = *(const uint4*)(xr3 + j * 4);
        acc[0][0] += __uint_as_float(a0.x + b.x);
        acc[0][1] += __uint_as_float(a0.y + b.y);
        acc[0][2] += __uint_as_float(a0.z + b.z);
        acc[0][3] += __uint_as_float(a0.w + b.w);
        acc[1][0] += __uint_as_float(a1.x + b.x);
        acc[1][1] += __uint_as_float(a1.y + b.y);
        acc[1][2] += __uint_as_float(a1.z + b.z);
        acc[1][3] += __uint_as_float(a1.w + b.w);
        acc[2][0] += __uint_as_float(a2.x + b.x);
        acc[2][1] += __uint_as_float(a2.y + b.y);
        acc[2][2] += __uint_as_float(a2.z + b.z);
        acc[2][3] += __uint_as_float(a2.w + b.w);
        acc[3][0] += __uint_as_float(a3.x + b.x);
        acc[3][1] += __uint_as_float(a3.y + b.y);
        acc[3][2] += __uint_as_float(a3.z + b.z);
        acc[3][3] += __uint_as_float(a3.w + b.w);
    }

    // ---- plain coalesced partial stores (no atomics) ----
    const int p = p0 + p_local;
    float* plane = pws + (size_t)kz * M * P;
    #pragma unroll
    for (int r = 0; r < TM; ++r) {
        plane[(size_t)(m0 + r) * P + p] =
            (acc[r][0] + acc[r][1]) + (acc[r][2] + acc[r][3]);
    }
}

__global__ __launch_bounds__(256) void lmul_reduce_kernel(
    const float* __restrict__ pws,   // [KS][M][P] partials
    const float* __restrict__ bias,  // [P]
    float*       __restrict__ out)   // [M][P]
{
    constexpr int MP4 = M * P / 4;   // 32768 float4s per plane
    const int idx = blockIdx.x * 256 + threadIdx.x;  // 0..32767

    const float4* w4 = (const float4*)pws;
    float4 s0 = w4[idx];
    float4 s1 = w4[idx + MP4];
    float4 s2 = w4[idx + 2 * MP4];
    float4 s3 = w4[idx + 3 * MP4];
    const float4 b4 = ((const float4*)bias)[idx & (P / 4 - 1)];

    float4 r;
    r.x = (s0.x + s1.x) + (s2.x + s3.x) + b4.x;
    r.y = (s0.y + s1.y) + (s2.y + s3.y) + b4.y;
    r.z = (s0.z + s1.z) + (s2.z + s3.z) + b4.z;
    r.w = (s0.w + s1.w) + (s2.w + s3.w) + b4.w;
    ((float4*)out)[idx] = r;
}

extern "C" void kernel_launch(void* const* d_in, const int* in_sizes, int n_in,
                              void* d_out, int out_size, void* d_ws, size_t ws_size,
                              hipStream_t stream) {
    const uint32_t* xb   = (const uint32_t*)d_in[0];  // x: (256,512) f32 bits
    const uint32_t* wb   = (const uint32_t*)d_in[1];  // weight: (512,512) f32 bits
    const float*    bias = (const float*)d_in[2];     // (512,)
    float*          out  = (float*)d_out;             // (256,512) f32
    float*          pws  = (float*)d_ws;              // KS*M*P floats = 2MB

    dim3 grid1(M / BM, P / BP, KS);  // (32, 4, 4) = 512 blocks, 2 per CU
    lmul_partial_kernel<<<grid1, dim3(256), 0, stream>>>(xb, wb, pws);

    dim3 grid2(M * P / 4 / 256);     // 128 blocks
    lmul_reduce_kernel<<<grid2, dim3(256), 0, stream>>>(pws, bias, out);
}

// Round 5
// 64.610 us; speedup vs baseline: 1.0159x; 1.0159x over previous
//
#include <hip/hip_runtime.h>
#include <stdint.h>

// out[m,p] = sum_k f32(bits(x[m,k]) + bits(weight[p,k]) - OFFSET) + bias[p]
// m=256, n=512, p=512. Pure VALU workload (uint add on bit patterns -> no MFMA).
//
// R5 = revert to R3 (measured best, 64.8us vs R4's 65.6):
//  - single kernel, k-split=4, fp32 atomicAdd combine (distinct addresses,
//    L2 absorbs the 4-way contention; tolerance covers reordering).
//  - R4's two-kernel no-atomic variant was NEUTRAL-to-worse: the extra
//    dispatch overhead cancels the atomic savings. Keep the single launch.
//  - TM=4 m-rows/thread: LDS traffic 256KB/CU, below the VALU floor.
//  - 512 blocks x 4 waves = 2048 waves = 2 waves/SIMD on all 256 CUs.
//  - 64KB LDS w-tile [pp][k], 16B-granule XOR swizzle: conflict-free
//    ds_write_b128 + ds_read_b128 (SQ_LDS_BANK_CONFLICT == 0 measured).
//  - offset correction folded in at staging (1 sub per w element per block).
//
// Measurement context: dur_us is dominated by ~60us of fixed harness cost
// (268MB ws re-poison = 40us at 84% HBM peak, + restores + dispatches).
// Kernel chain ~4-5us vs ~2.5us structural floor (VALU 4096 cyc/CU = 1.7us).

#define OFFSET_FP32 1064828928u

constexpr int M = 256;
constexpr int N = 512;
constexpr int P = 512;

constexpr int BP = 128;     // p cols per block
constexpr int BM = 8;       // m rows per block
constexpr int TM = 4;       // m rows per thread
constexpr int KS = 4;       // k-split factor
constexpr int KT = N / KS;  // 128 k per block

__global__ __launch_bounds__(256) void lmul_linear_kernel(
    const uint32_t* __restrict__ xb,   // [M][N] bit patterns of x
    const uint32_t* __restrict__ wb,   // [P][N] bit patterns of weight
    const float*    __restrict__ bias, // [P]
    float*          __restrict__ out)  // [M][P], pre-zeroed
{
    __shared__ uint32_t Bs[BP * KT];   // 64 KB, row pp at pp*KT, granules XOR-swizzled

    const int tid     = threadIdx.x;
    const int p_local = tid & (BP - 1);                            // 0..127
    const int m_quad  = __builtin_amdgcn_readfirstlane(tid >> 7);  // 0..1, wave-uniform

    const int p0 = blockIdx.y * BP;
    const int m0 = blockIdx.x * BM + m_quad * TM;
    const int k0 = blockIdx.z * KT;

    // ---- stage w tile [128p][128k] = 64KB: 256 threads x 16 uint4 ----
    const int sg = tid & 31;  // 16B granule within row, coalesced
    const int sr = tid >> 5;  // 0..7
    const uint32_t* wbase = wb + (size_t)p0 * N + k0;
    #pragma unroll
    for (int j = 0; j < 16; ++j) {
        const int pp = sr + j * 8;
        uint4 v = *(const uint4*)(wbase + (size_t)pp * N + sg * 4);
        v.x -= OFFSET_FP32; v.y -= OFFSET_FP32;   // fold offset at staging
        v.z -= OFFSET_FP32; v.w -= OFFSET_FP32;
        const int g = sg ^ (pp & 7);              // swizzle: conflict-free b128 r/w
        *(uint4*)&Bs[pp * KT + g * 4] = v;
    }
    __syncthreads();

    // ---- compute: 32 steps x (1 ds_read_b128 + 4 uniform uint4 a-loads + 32 VALU) ----
    const uint32_t* xr0 = xb + (size_t)(m0 + 0) * N + k0;
    const uint32_t* xr1 = xb + (size_t)(m0 + 1) * N + k0;
    const uint32_t* xr2 = xb + (size_t)(m0 + 2) * N + k0;
    const uint32_t* xr3 = xb + (size_t)(m0 + 3) * N + k0;

    float acc[TM][4] = {};
    const uint32_t* brow = &Bs[p_local * KT];
    const int rot = p_local & 7;

    #pragma unroll 8
    for (int j = 0; j < KT / 4; ++j) {
        const uint4 b  = *(const uint4*)&brow[(j ^ rot) * 4];
        const uint4 a0 = *(const uint4*)(xr0 + j * 4);  // wave-uniform -> scalar path
        const uint4 a1 = *(const uint4*)(xr1 + j * 4);
        const uint4 a2 = *(const uint4*)(xr2 + j * 4);
        const uint4 a3 = *(const uint4*)(xr3 + j * 4);
        acc[0][0] += __uint_as_float(a0.x + b.x);
        acc[0][1] += __uint_as_float(a0.y + b.y);
        acc[0][2] += __uint_as_float(a0.z + b.z);
        acc[0][3] += __uint_as_float(a0.w + b.w);
        acc[1][0] += __uint_as_float(a1.x + b.x);
        acc[1][1] += __uint_as_float(a1.y + b.y);
        acc[1][2] += __uint_as_float(a1.z + b.z);
        acc[1][3] += __uint_as_float(a1.w + b.w);
        acc[2][0] += __uint_as_float(a2.x + b.x);
        acc[2][1] += __uint_as_float(a2.y + b.y);
        acc[2][2] += __uint_as_float(a2.z + b.z);
        acc[2][3] += __uint_as_float(a2.w + b.w);
        acc[3][0] += __uint_as_float(a3.x + b.x);
        acc[3][1] += __uint_as_float(a3.y + b.y);
        acc[3][2] += __uint_as_float(a3.z + b.z);
        acc[3][3] += __uint_as_float(a3.w + b.w);
    }

    // ---- combine: one k0==0 block per output adds the bias ----
    const int p  = p0 + p_local;
    const float bv = (k0 == 0) ? bias[p] : 0.0f;
    #pragma unroll
    for (int r = 0; r < TM; ++r) {
        const float s = (acc[r][0] + acc[r][1]) + (acc[r][2] + acc[r][3]) + bv;
        atomicAdd(&out[(size_t)(m0 + r) * P + p], s);
    }
}

extern "C" void kernel_launch(void* const* d_in, const int* in_sizes, int n_in,
                              void* d_out, int out_size, void* d_ws, size_t ws_size,
                              hipStream_t stream) {
    const uint32_t* xb   = (const uint32_t*)d_in[0];  // x: (256,512) f32 bits
    const uint32_t* wb   = (const uint32_t*)d_in[1];  // weight: (512,512) f32 bits
    const float*    bias = (const float*)d_in[2];     // (512,)
    float*          out  = (float*)d_out;             // (256,512) f32

    hipMemsetAsync(d_out, 0, (size_t)out_size * sizeof(float), stream);

    dim3 grid(M / BM, P / BP, KS);  // (32, 4, 4) = 512 blocks, 2 per CU
    dim3 block(256);                // 4 waves -> with 2 blocks/CU: 2 waves/SIMD
    lmul_linear_kernel<<<grid, block, 0, stream>>>(xb, wb, bias, out);
}